// Round 5
// baseline (340.924 us; speedup 1.0000x reference)
//
#include <hip/hip_runtime.h>

// LightGCN, 3-layer propagation, 200001 nodes, D=64.
// Round 11: discriminate latency(T1) vs bandwidth(T2) theories for the
// SpMM phase. Round-10 LDS record staging was neutral (312.8->314.8)
// -> record epoch not binding. This round: (a) revert staging; (b)
// 16-deep gather unroll with sentinel-padded edge_s (16 zero records
// after nnz) so record loads need no clamping; rows of mean len 10 run
// ONE records->gathers epoch instead of two. If T1, spmm drops ~25%;
// if unchanged, the ~3.9TB/s random-fill plateau (T2) is confirmed and
// the next lever is traffic reduction.

#define N_NODES 200001
#define NUP1    100001            // NUM_USERS + 1
#define D       64
#define DV      16                // float4/ushort4 per row (init/final)
#define DV8     8                 // uint4 (8 bf16) per row (spmm)
#define CHUNK   512
#define NCHUNK  ((N_NODES + CHUNK - 1) / CHUNK)   // 391
#define T_TILE  4096              // edges per pass1 block
#define EPT     16                // edges per thread in pass1
#define CAP     6144              // bucket capacity (exp ~5115, +14 sigma)
#define REP     2                 // counter replicas (by block parity)
#define HALFCAP (CAP / REP)       // 3072 (exp ~2558, +10 sigma)
#define CNT_STRIDE 16             // ints; one counter per 64B line
#define CNT_TOTAL  (NCHUNK * REP * CNT_STRIDE)   // 12512 ints

__device__ __forceinline__ unsigned short f2bf(float f) {
  unsigned u = __float_as_uint(f);
  unsigned r = (u + 0x7FFFu + ((u >> 16) & 1u)) >> 16;   // RNE
  return (unsigned short)r;
}
__device__ __forceinline__ float bf2f(unsigned short h) {
  return __uint_as_float(((unsigned)h) << 16);
}
__device__ __forceinline__ float bflo(unsigned u) { return __uint_as_float(u << 16); }
__device__ __forceinline__ float bfhi(unsigned u) { return __uint_as_float(u & 0xFFFF0000u); }

// Build x0 (bf16) from fp32 embeddings; also zero padded bucket counters.
__global__ __launch_bounds__(256) void init_kernel(
    const float4* __restrict__ user_emb,
    const float4* __restrict__ item_emb,
    ushort4* __restrict__ x0,
    int* __restrict__ bucket_cnt) {
  int idx = blockIdx.x * 256 + threadIdx.x;
  if (idx < CNT_TOTAL) bucket_cnt[idx] = 0;
  if (idx >= N_NODES * DV) return;
  int n = idx >> 4;
  int j = idx & 15;
  float4 v = (n < NUP1) ? user_emb[idx]
                        : item_emb[(size_t)(n - 100000) * DV + j];
  x0[idx] = make_ushort4(f2bf(v.x), f2bf(v.y), f2bf(v.z), f2bf(v.w));
}

// Pass 1: multisplit edges into 391 chunk-buckets (private per-block runs).
// Counter for (bucket b, replica r) at bucket_cnt[(b*REP+r)*CNT_STRIDE];
// replica r = blockIdx.x & 1 owns sub-region [b*CAP + r*HALFCAP, ...).
__global__ __launch_bounds__(256) void pass1_bucket(
    const int*   __restrict__ rows,
    const int*   __restrict__ cols,
    const float* __restrict__ vals,
    int*  __restrict__ bucket_cnt,
    int2* __restrict__ bucket_arr,
    int nnz) {
  __shared__ int lcount[NCHUNK];
  __shared__ int lbase[NCHUNK];
  int t = threadIdx.x;
  for (int i = t; i < NCHUNK; i += 256) lcount[i] = 0;
  __syncthreads();
  long base = (long)blockIdx.x * T_TILE;
  int rep = blockIdx.x & (REP - 1);
  int2 pk[EPT];
  int  meta[EPT];
#pragma unroll
  for (int k = 0; k < EPT; ++k) {
    long e = base + t + (long)k * 256;
    if (e < nnz) {
      int r = rows[e];
      int b = r >> 9;                          // chunk bucket (0..390)
      int rank = atomicAdd(&lcount[b], 1);     // LDS atomic
      pk[k] = make_int2(((r & 511) << 18) | cols[e], __float_as_int(vals[e]));
      meta[k] = (rank << 9) | b;               // rank<4096 (12b) | b (9b)
    } else {
      meta[k] = -1;
    }
  }
  __syncthreads();
  for (int b = t; b < NCHUNK; b += 256) {
    int c = lcount[b];
    lbase[b] = (c > 0)
        ? (b * CAP + rep * HALFCAP +
           atomicAdd(&bucket_cnt[(b * REP + rep) * CNT_STRIDE], c))
        : 0;
  }
  __syncthreads();
#pragma unroll
  for (int k = 0; k < EPT; ++k) {
    if (meta[k] >= 0) {
      int b = meta[k] & 511;
      int rank = meta[k] >> 9;
      bucket_arr[lbase[b] + rank] = pk[k];
    }
  }
}

// Parallel exclusive scan of 391 combined chunk counts (one block).
// Also writes the 16 sentinel records past nnz (col=0, val=0) that let
// the spmm 16-unroll skip record clamping.
__global__ __launch_bounds__(512) void scan_chunks_kernel(
    const int* __restrict__ cnt, int* __restrict__ off,
    int* __restrict__ row_ptr, int2* __restrict__ edge_s, int nnz) {
  __shared__ int sh[512];
  int t = threadIdx.x;
  if (t < 16) edge_s[nnz + t] = make_int2(0, 0);
  int v = (t < NCHUNK)
      ? cnt[(t * REP + 0) * CNT_STRIDE] + cnt[(t * REP + 1) * CNT_STRIDE]
      : 0;
  sh[t] = v;
  __syncthreads();
  for (int o = 1; o < 512; o <<= 1) {
    int u = (t >= o) ? sh[t - o] : 0;
    __syncthreads();
    sh[t] += u;
    __syncthreads();
  }
  if (t < NCHUNK) off[t] = sh[t] - v;   // exclusive prefix
  if (t == 0) row_ptr[N_NODES] = nnz;
}

// Fused per-chunk: LDS histogram -> LDS scan -> row_ptr write -> scatter
// into final CSR order with LDS cursors. Reads both replica segments.
__global__ __launch_bounds__(256) void build_csr_chunk(
    const int*  __restrict__ bucket_cnt,
    const int2* __restrict__ bucket_arr,
    const int*  __restrict__ chunk_off,
    int*  __restrict__ row_ptr,
    int2* __restrict__ edge_s) {
  __shared__ int lcnt[CHUNK];     // histogram, then cursors
  __shared__ int tsum[256];
  int b = blockIdx.x, t = threadIdx.x;
  lcnt[t] = 0; lcnt[t + 256] = 0;
  __syncthreads();
  int ne0 = bucket_cnt[(b * REP + 0) * CNT_STRIDE];
  int ne1 = bucket_cnt[(b * REP + 1) * CNT_STRIDE];
  const int2* ba = bucket_arr + (size_t)b * CAP;
  for (int i = t; i < ne0; i += 256)
    atomicAdd(&lcnt[ba[i].x >> 18], 1);
  for (int i = t; i < ne1; i += 256)
    atomicAdd(&lcnt[ba[HALFCAP + i].x >> 18], 1);
  __syncthreads();
  int base = t * 2;
  int l0 = lcnt[base], l1 = lcnt[base + 1];
  int s = l0 + l1;
  tsum[t] = s;
  __syncthreads();
  for (int o = 1; o < 256; o <<= 1) {
    int v = (t >= o) ? tsum[t - o] : 0;
    __syncthreads();
    tsum[t] += v;
    __syncthreads();
  }
  int run = tsum[t] - s + chunk_off[b];
  int row0 = b * CHUNK;
  if (row0 + base < N_NODES) row_ptr[row0 + base] = run;
  lcnt[base] = run;
  run += l0;
  if (row0 + base + 1 < N_NODES) row_ptr[row0 + base + 1] = run;
  lcnt[base + 1] = run;
  __syncthreads();
  for (int i = t; i < ne0; i += 256) {
    int2 ed = ba[i];
    int p = atomicAdd(&lcnt[ed.x >> 18], 1);
    edge_s[p] = make_int2(ed.x & 0x3FFFF, ed.y);
  }
  for (int i = t; i < ne1; i += 256) {
    int2 ed = ba[HALFCAP + i];
    int p = atomicAdd(&lcnt[ed.x >> 18], 1);
    edge_s[p] = make_int2(ed.x & 0x3FFFF, ed.y);
  }
}

// ---------- SpMM, 16-deep gather unroll ----------
// 8 lanes/row, 16 B (8 bf16 dims) per lane. One iteration issues 16
// record loads (no clamp; sentinel-padded) + 16 gathers back-to-back:
// mean-10 rows complete in ONE records->gathers latency epoch.
// Over-read records belong to following rows (valid cols); their vals
// are masked to 0.

#define ACCUM(V, XV) {                                    \
    a0 += (V) * bflo((XV).x); a1 += (V) * bfhi((XV).x);   \
    a2 += (V) * bflo((XV).y); a3 += (V) * bfhi((XV).y);   \
    a4 += (V) * bflo((XV).z); a5 += (V) * bfhi((XV).z);   \
    a6 += (V) * bflo((XV).w); a7 += (V) * bfhi((XV).w); }

#define SPMM_BODY                                                   \
  int t = blockIdx.x * 256 + threadIdx.x;                           \
  int r = t >> 3;                                                   \
  int j = t & 7;                                                    \
  float a0 = 0.f, a1 = 0.f, a2 = 0.f, a3 = 0.f;                     \
  float a4 = 0.f, a5 = 0.f, a6 = 0.f, a7 = 0.f;                     \
  {                                                                 \
    int s = row_ptr[r];                                             \
    int e = row_ptr[r + 1];                                         \
    for (int g = s; g < e; g += 16) {                               \
      int2 q0 = edge_s[g + 0];  int2 q1 = edge_s[g + 1];            \
      int2 q2 = edge_s[g + 2];  int2 q3 = edge_s[g + 3];            \
      int2 q4 = edge_s[g + 4];  int2 q5 = edge_s[g + 5];            \
      int2 q6 = edge_s[g + 6];  int2 q7 = edge_s[g + 7];            \
      int2 q8 = edge_s[g + 8];  int2 q9 = edge_s[g + 9];            \
      int2 qA = edge_s[g + 10]; int2 qB = edge_s[g + 11];           \
      int2 qC = edge_s[g + 12]; int2 qD = edge_s[g + 13];           \
      int2 qE = edge_s[g + 14]; int2 qF = edge_s[g + 15];           \
      uint4 g0 = x[(size_t)q0.x * DV8 + j];                         \
      uint4 g1 = x[(size_t)q1.x * DV8 + j];                         \
      uint4 g2 = x[(size_t)q2.x * DV8 + j];                         \
      uint4 g3 = x[(size_t)q3.x * DV8 + j];                         \
      uint4 g4 = x[(size_t)q4.x * DV8 + j];                         \
      uint4 g5 = x[(size_t)q5.x * DV8 + j];                         \
      uint4 g6 = x[(size_t)q6.x * DV8 + j];                         \
      uint4 g7 = x[(size_t)q7.x * DV8 + j];                         \
      uint4 g8 = x[(size_t)q8.x * DV8 + j];                         \
      uint4 g9 = x[(size_t)q9.x * DV8 + j];                         \
      uint4 gA = x[(size_t)qA.x * DV8 + j];                         \
      uint4 gB = x[(size_t)qB.x * DV8 + j];                         \
      uint4 gC = x[(size_t)qC.x * DV8 + j];                         \
      uint4 gD = x[(size_t)qD.x * DV8 + j];                         \
      uint4 gE = x[(size_t)qE.x * DV8 + j];                         \
      uint4 gF = x[(size_t)qF.x * DV8 + j];                         \
      float v0 = __int_as_float(q0.y);                              \
      float v1 = (g + 1  < e) ? __int_as_float(q1.y) : 0.f;         \
      float v2 = (g + 2  < e) ? __int_as_float(q2.y) : 0.f;         \
      float v3 = (g + 3  < e) ? __int_as_float(q3.y) : 0.f;         \
      float v4 = (g + 4  < e) ? __int_as_float(q4.y) : 0.f;         \
      float v5 = (g + 5  < e) ? __int_as_float(q5.y) : 0.f;         \
      float v6 = (g + 6  < e) ? __int_as_float(q6.y) : 0.f;         \
      float v7 = (g + 7  < e) ? __int_as_float(q7.y) : 0.f;         \
      float v8 = (g + 8  < e) ? __int_as_float(q8.y) : 0.f;         \
      float v9 = (g + 9  < e) ? __int_as_float(q9.y) : 0.f;         \
      float vA = (g + 10 < e) ? __int_as_float(qA.y) : 0.f;         \
      float vB = (g + 11 < e) ? __int_as_float(qB.y) : 0.f;         \
      float vC = (g + 12 < e) ? __int_as_float(qC.y) : 0.f;         \
      float vD = (g + 13 < e) ? __int_as_float(qD.y) : 0.f;         \
      float vE = (g + 14 < e) ? __int_as_float(qE.y) : 0.f;         \
      float vF = (g + 15 < e) ? __int_as_float(qF.y) : 0.f;         \
      ACCUM(v0, g0); ACCUM(v1, g1); ACCUM(v2, g2); ACCUM(v3, g3);   \
      ACCUM(v4, g4); ACCUM(v5, g5); ACCUM(v6, g6); ACCUM(v7, g7);   \
      ACCUM(v8, g8); ACCUM(v9, g9); ACCUM(vA, gA); ACCUM(vB, gB);   \
      ACCUM(vC, gC); ACCUM(vD, gD); ACCUM(vE, gE); ACCUM(vF, gF);   \
    }                                                               \
  }

__global__ __launch_bounds__(256) void spmm_bf16_kernel(
    const int*  __restrict__ row_ptr,
    const int2* __restrict__ edge_s,
    const uint4* __restrict__ x,
    uint4*       __restrict__ y) {
  if ((blockIdx.x * 256 + threadIdx.x) >> 3 >= N_NODES) return;
  SPMM_BODY
  uint4 o;
  o.x = ((unsigned)f2bf(a1) << 16) | f2bf(a0);
  o.y = ((unsigned)f2bf(a3) << 16) | f2bf(a2);
  o.z = ((unsigned)f2bf(a5) << 16) | f2bf(a4);
  o.w = ((unsigned)f2bf(a7) << 16) | f2bf(a6);
  y[t] = o;
}

// Layer-3 SpMM fused with the final average:
// out[rowmap(r)] = 0.25*(emb_fp32 + y1 + y2 + a); y3 never materialized.
// Epilogue row reads hoisted above the edge loop to overlap gathers.
__global__ __launch_bounds__(256) void spmm_final_kernel(
    const int*  __restrict__ row_ptr,
    const int2* __restrict__ edge_s,
    const uint4* __restrict__ x,          // = y2 (gather input)
    const uint4* __restrict__ y1u,
    const float4* __restrict__ user_emb,
    const float4* __restrict__ item_emb,
    float4* __restrict__ out) {
  int gt0 = blockIdx.x * 256 + threadIdx.x;
  if (gt0 < DV) out[(size_t)NUP1 * DV + gt0] = make_float4(0.f, 0.f, 0.f, 0.f);
  if (gt0 >> 3 >= N_NODES) return;
  int rr = gt0 >> 3;
  int jj = threadIdx.x & 7;
  uint4 w1 = y1u[(size_t)rr * DV8 + jj];
  uint4 w2 = x  [(size_t)rr * DV8 + jj];   // y2 row (x aliases y2)
  float4 f0, f1;
  if (rr < NUP1) {
    size_t eb = (size_t)rr * DV + 2 * jj;
    f0 = user_emb[eb];
    f1 = user_emb[eb + 1];
  } else {
    size_t ib = (size_t)(rr - 100000) * DV + 2 * jj;
    f0 = item_emb[ib];
    f1 = item_emb[ib + 1];
  }
  SPMM_BODY
  int rm = (r < NUP1) ? r : r + 1;
  float4 o0, o1;
  o0.x = 0.25f * (f0.x + bflo(w1.x) + bflo(w2.x) + a0);
  o0.y = 0.25f * (f0.y + bfhi(w1.x) + bfhi(w2.x) + a1);
  o0.z = 0.25f * (f0.z + bflo(w1.y) + bflo(w2.y) + a2);
  o0.w = 0.25f * (f0.w + bfhi(w1.y) + bfhi(w2.y) + a3);
  o1.x = 0.25f * (f1.x + bflo(w1.z) + bflo(w2.z) + a4);
  o1.y = 0.25f * (f1.y + bfhi(w1.z) + bfhi(w2.z) + a5);
  o1.z = 0.25f * (f1.z + bflo(w1.w) + bflo(w2.w) + a6);
  o1.w = 0.25f * (f1.w + bfhi(w1.w) + bfhi(w2.w) + a7);
  out[(size_t)rm * DV + 2 * j]     = o0;
  out[(size_t)rm * DV + 2 * j + 1] = o1;
}

static inline char* align16(char* p) {
  return (char*)(((uintptr_t)p + 15) & ~(uintptr_t)15);
}

extern "C" void kernel_launch(void* const* d_in, const int* in_sizes, int n_in,
                              void* d_out, int out_size, void* d_ws, size_t ws_size,
                              hipStream_t stream) {
  const float* user_emb = (const float*)d_in[0];
  const float* item_emb = (const float*)d_in[1];
  const int*   rows     = (const int*)d_in[2];
  const int*   cols     = (const int*)d_in[3];
  const float* vals     = (const float*)d_in[4];
  const int    nnz      = in_sizes[2];

  const size_t xbytes = (size_t)N_NODES * D * sizeof(unsigned short); // 25.6 MB
  char* p = (char*)d_ws;
  ushort4* x0 = (ushort4*)p;  p += xbytes;
  ushort4* y1 = (ushort4*)p;  p += xbytes;
  ushort4* y2 = (ushort4*)p;  p += xbytes;
  ushort4* y3 = (ushort4*)p;  p += xbytes;  // scratch window for bucket_arr
  // bucket_arr aliases y2+y3 (51.2 MB window; needs 19.2 MB): fully consumed
  // by build_csr_chunk before layer-2 spmm writes y2.
  int2* bucket_arr = (int2*)y2;
  (void)y3;
  p = align16(p);
  int2* edge_s = (int2*)p;    p += (size_t)(nnz + 16) * sizeof(int2);
  p = align16(p);
  int* row_ptr = (int*)p;     p += (size_t)(N_NODES + 1) * sizeof(int);
  p = align16(p);
  int* chunk_off = (int*)p;   p += (size_t)NCHUNK * sizeof(int);
  p = align16(p);
  int* bucket_cnt = (int*)p;  p += (size_t)CNT_TOTAL * sizeof(int);

  float* out = (float*)d_out;

  const int row_elems = N_NODES * DV;                // 3,200,016
  const int node_grid = (row_elems + 255) / 256;     // 12501
  const int spmm_grid = (N_NODES * DV8 + 255) / 256; // 6251
  const int tile_grid = (nnz + T_TILE - 1) / T_TILE;

  init_kernel<<<node_grid, 256, 0, stream>>>(
      (const float4*)user_emb, (const float4*)item_emb, x0, bucket_cnt);
  pass1_bucket<<<tile_grid, 256, 0, stream>>>(
      rows, cols, vals, bucket_cnt, bucket_arr, nnz);
  scan_chunks_kernel<<<1, 512, 0, stream>>>(bucket_cnt, chunk_off, row_ptr,
                                            edge_s, nnz);
  build_csr_chunk<<<NCHUNK, 256, 0, stream>>>(
      bucket_cnt, bucket_arr, chunk_off, row_ptr, edge_s);

  spmm_bf16_kernel<<<spmm_grid, 256, 0, stream>>>(
      row_ptr, edge_s, (const uint4*)x0, (uint4*)y1);
  spmm_bf16_kernel<<<spmm_grid, 256, 0, stream>>>(
      row_ptr, edge_s, (const uint4*)y1, (uint4*)y2);
  spmm_final_kernel<<<spmm_grid, 256, 0, stream>>>(
      row_ptr, edge_s, (const uint4*)y2, (const uint4*)y1,
      (const float4*)user_emb, (const float4*)item_emb, (float4*)out);
}

// Round 6
// 305.512 us; speedup vs baseline: 1.1159x; 1.1159x over previous
//
#include <hip/hip_runtime.h>

// LightGCN, 3-layer propagation, 200001 nodes, D=64.
// Round 12: revert spmm to round-9 code (best: 312.8us; r10 staging
// neutral, r11 16-unroll regressed 340.9 -> SpMM is at its ~3.9TB/s
// traffic plateau, T2 confirmed). Attack the serial pre-pipeline
// instead: (a) fuse init||pass1 into one block-range-split kernel
// (independent work; bucket_cnt zeroing via hipMemsetAsync);
// (b) inline the 391-chunk prefix scan into build_csr_chunk (each
// block recomputes it in LDS, ~1us, deletes the 1-block scan kernel
// and its serialization bubble). 6 enqueues vs 8.

#define N_NODES 200001
#define NUP1    100001            // NUM_USERS + 1
#define D       64
#define DV      16                // float4/ushort4 per row (init/final)
#define DV8     8                 // uint4 (8 bf16) per row (spmm)
#define CHUNK   512
#define NCHUNK  ((N_NODES + CHUNK - 1) / CHUNK)   // 391
#define T_TILE  4096              // edges per pass1 block
#define EPT     16                // edges per thread in pass1
#define CAP     6144              // bucket capacity (exp ~5115, +14 sigma)
#define REP     2                 // counter replicas (by block parity)
#define HALFCAP (CAP / REP)       // 3072 (exp ~2558, +10 sigma)
#define CNT_STRIDE 16             // ints; one counter per 64B line
#define CNT_TOTAL  (NCHUNK * REP * CNT_STRIDE)   // 12512 ints

__device__ __forceinline__ unsigned short f2bf(float f) {
  unsigned u = __float_as_uint(f);
  unsigned r = (u + 0x7FFFu + ((u >> 16) & 1u)) >> 16;   // RNE
  return (unsigned short)r;
}
__device__ __forceinline__ float bf2f(unsigned short h) {
  return __uint_as_float(((unsigned)h) << 16);
}
__device__ __forceinline__ float bflo(unsigned u) { return __uint_as_float(u << 16); }
__device__ __forceinline__ float bfhi(unsigned u) { return __uint_as_float(u & 0xFFFF0000u); }

// Fused setup: blocks [0, tile_grid) run pass1 multisplit; blocks
// [tile_grid, ...) build x0 (bf16) from fp32 embeddings.
// bucket_cnt is pre-zeroed by hipMemsetAsync on the stream.
__global__ __launch_bounds__(256) void setup_kernel(
    const float4* __restrict__ user_emb,
    const float4* __restrict__ item_emb,
    ushort4* __restrict__ x0,
    const int*   __restrict__ rows,
    const int*   __restrict__ cols,
    const float* __restrict__ vals,
    int*  __restrict__ bucket_cnt,
    int2* __restrict__ bucket_arr,
    int nnz, int tile_grid) {
  __shared__ int lcount[NCHUNK];
  __shared__ int lbase[NCHUNK];
  int t = threadIdx.x;
  if (blockIdx.x >= tile_grid) {
    // ---- init path ----
    int idx = (blockIdx.x - tile_grid) * 256 + t;
    if (idx >= N_NODES * DV) return;
    int n = idx >> 4;
    int j = idx & 15;
    float4 v = (n < NUP1) ? user_emb[idx]
                          : item_emb[(size_t)(n - 100000) * DV + j];
    x0[idx] = make_ushort4(f2bf(v.x), f2bf(v.y), f2bf(v.z), f2bf(v.w));
    return;
  }
  // ---- pass1 multisplit path ----
  for (int i = t; i < NCHUNK; i += 256) lcount[i] = 0;
  __syncthreads();
  long base = (long)blockIdx.x * T_TILE;
  int rep = blockIdx.x & (REP - 1);
  int2 pk[EPT];
  int  meta[EPT];
#pragma unroll
  for (int k = 0; k < EPT; ++k) {
    long e = base + t + (long)k * 256;
    if (e < nnz) {
      int r = rows[e];
      int b = r >> 9;                          // chunk bucket (0..390)
      int rank = atomicAdd(&lcount[b], 1);     // LDS atomic
      pk[k] = make_int2(((r & 511) << 18) | cols[e], __float_as_int(vals[e]));
      meta[k] = (rank << 9) | b;               // rank<4096 (12b) | b (9b)
    } else {
      meta[k] = -1;
    }
  }
  __syncthreads();
  for (int b = t; b < NCHUNK; b += 256) {
    int c = lcount[b];
    lbase[b] = (c > 0)
        ? (b * CAP + rep * HALFCAP +
           atomicAdd(&bucket_cnt[(b * REP + rep) * CNT_STRIDE], c))
        : 0;
  }
  __syncthreads();
#pragma unroll
  for (int k = 0; k < EPT; ++k) {
    if (meta[k] >= 0) {
      int b = meta[k] & 511;
      int rank = meta[k] >> 9;
      bucket_arr[lbase[b] + rank] = pk[k];
    }
  }
}

// Fused per-chunk: inline 391-chunk prefix scan -> LDS histogram ->
// LDS row scan -> row_ptr write -> scatter into final CSR order with
// LDS cursors. Reads both replica counter segments.
__global__ __launch_bounds__(256) void build_csr_chunk(
    const int*  __restrict__ bucket_cnt,
    const int2* __restrict__ bucket_arr,
    int*  __restrict__ row_ptr,
    int2* __restrict__ edge_s, int nnz) {
  __shared__ int lcnt[CHUNK];     // histogram, then cursors
  __shared__ int tsum[256];
  __shared__ int sc0[256];
  __shared__ int poff[256];
  int b = blockIdx.x, t = threadIdx.x;
  // ---- Phase A: chunk-offset scan (each block computes full prefix) ----
  int i0 = 2 * t, i1 = 2 * t + 1;
  int c0 = (i0 < NCHUNK)
      ? bucket_cnt[(i0 * REP + 0) * CNT_STRIDE] +
        bucket_cnt[(i0 * REP + 1) * CNT_STRIDE] : 0;
  int c1 = (i1 < NCHUNK)
      ? bucket_cnt[(i1 * REP + 0) * CNT_STRIDE] +
        bucket_cnt[(i1 * REP + 1) * CNT_STRIDE] : 0;
  int ps = c0 + c1;
  sc0[t] = c0;
  tsum[t] = ps;
  __syncthreads();
  for (int o = 1; o < 256; o <<= 1) {
    int v = (t >= o) ? tsum[t - o] : 0;
    __syncthreads();
    tsum[t] += v;
    __syncthreads();
  }
  poff[t] = tsum[t] - ps;          // exclusive pair prefix
  __syncthreads();
  int chunk_off_b = poff[b >> 1] + ((b & 1) ? sc0[b >> 1] : 0);
  if (b == 0 && t == 0) row_ptr[N_NODES] = nnz;
  __syncthreads();                 // tsum reused below
  // ---- Phase B: histogram + row scan + scatter ----
  lcnt[t] = 0; lcnt[t + 256] = 0;
  __syncthreads();
  int ne0 = bucket_cnt[(b * REP + 0) * CNT_STRIDE];
  int ne1 = bucket_cnt[(b * REP + 1) * CNT_STRIDE];
  const int2* ba = bucket_arr + (size_t)b * CAP;
  for (int i = t; i < ne0; i += 256)
    atomicAdd(&lcnt[ba[i].x >> 18], 1);
  for (int i = t; i < ne1; i += 256)
    atomicAdd(&lcnt[ba[HALFCAP + i].x >> 18], 1);
  __syncthreads();
  int base = t * 2;
  int l0 = lcnt[base], l1 = lcnt[base + 1];
  int s = l0 + l1;
  tsum[t] = s;
  __syncthreads();
  for (int o = 1; o < 256; o <<= 1) {
    int v = (t >= o) ? tsum[t - o] : 0;
    __syncthreads();
    tsum[t] += v;
    __syncthreads();
  }
  int run = tsum[t] - s + chunk_off_b;
  int row0 = b * CHUNK;
  if (row0 + base < N_NODES) row_ptr[row0 + base] = run;
  lcnt[base] = run;
  run += l0;
  if (row0 + base + 1 < N_NODES) row_ptr[row0 + base + 1] = run;
  lcnt[base + 1] = run;
  __syncthreads();
  for (int i = t; i < ne0; i += 256) {
    int2 ed = ba[i];
    int p = atomicAdd(&lcnt[ed.x >> 18], 1);
    edge_s[p] = make_int2(ed.x & 0x3FFFF, ed.y);
  }
  for (int i = t; i < ne1; i += 256) {
    int2 ed = ba[HALFCAP + i];
    int p = atomicAdd(&lcnt[ed.x >> 18], 1);
    edge_s[p] = make_int2(ed.x & 0x3FFFF, ed.y);
  }
}

// Row-parallel bf16 SpMM: 8 lanes/row, 16 B (8 bf16 dims) per lane.
// Edge loop in clamped groups of 8: 8 record loads + 8 gathers issued
// back-to-back every iteration; padded slots contribute v=0.
// (round-9 code verbatim: best measured SpMM variant)
#define SPMM_BODY                                                   \
  int t = blockIdx.x * 256 + threadIdx.x;                           \
  int r = t >> 3;                                                   \
  int j = t & 7;                                                    \
  float a0 = 0.f, a1 = 0.f, a2 = 0.f, a3 = 0.f;                     \
  float a4 = 0.f, a5 = 0.f, a6 = 0.f, a7 = 0.f;                     \
  {                                                                 \
    int s = row_ptr[r];                                             \
    int e = row_ptr[r + 1];                                         \
    int last = e - 1;                                               \
    for (int g = s; g < e; g += 8) {                                \
      int2 e0 = edge_s[min(g + 0, last)];                           \
      int2 e1 = edge_s[min(g + 1, last)];                           \
      int2 e2 = edge_s[min(g + 2, last)];                           \
      int2 e3 = edge_s[min(g + 3, last)];                           \
      int2 e4 = edge_s[min(g + 4, last)];                           \
      int2 e5 = edge_s[min(g + 5, last)];                           \
      int2 e6 = edge_s[min(g + 6, last)];                           \
      int2 e7 = edge_s[min(g + 7, last)];                           \
      uint4 x0 = x[(size_t)e0.x * DV8 + j];                         \
      uint4 x1 = x[(size_t)e1.x * DV8 + j];                         \
      uint4 x2 = x[(size_t)e2.x * DV8 + j];                         \
      uint4 x3 = x[(size_t)e3.x * DV8 + j];                         \
      uint4 x4 = x[(size_t)e4.x * DV8 + j];                         \
      uint4 x5 = x[(size_t)e5.x * DV8 + j];                         \
      uint4 x6 = x[(size_t)e6.x * DV8 + j];                         \
      uint4 x7 = x[(size_t)e7.x * DV8 + j];                         \
      float v0 = __int_as_float(e0.y);                              \
      float v1 = (g + 1 < e) ? __int_as_float(e1.y) : 0.f;          \
      float v2 = (g + 2 < e) ? __int_as_float(e2.y) : 0.f;          \
      float v3 = (g + 3 < e) ? __int_as_float(e3.y) : 0.f;          \
      float v4 = (g + 4 < e) ? __int_as_float(e4.y) : 0.f;          \
      float v5 = (g + 5 < e) ? __int_as_float(e5.y) : 0.f;          \
      float v6 = (g + 6 < e) ? __int_as_float(e6.y) : 0.f;          \
      float v7 = (g + 7 < e) ? __int_as_float(e7.y) : 0.f;          \
      ACCUM(v0, x0); ACCUM(v1, x1); ACCUM(v2, x2); ACCUM(v3, x3);   \
      ACCUM(v4, x4); ACCUM(v5, x5); ACCUM(v6, x6); ACCUM(v7, x7);   \
    }                                                               \
  }

#define ACCUM(V, XV) {                                    \
    a0 += (V) * bflo((XV).x); a1 += (V) * bfhi((XV).x);   \
    a2 += (V) * bflo((XV).y); a3 += (V) * bfhi((XV).y);   \
    a4 += (V) * bflo((XV).z); a5 += (V) * bfhi((XV).z);   \
    a6 += (V) * bflo((XV).w); a7 += (V) * bfhi((XV).w); }

__global__ __launch_bounds__(256) void spmm_bf16_kernel(
    const int*  __restrict__ row_ptr,
    const int2* __restrict__ edge_s,
    const uint4* __restrict__ x,
    uint4*       __restrict__ y) {
  if ((blockIdx.x * 256 + threadIdx.x) >> 3 >= N_NODES) return;
  SPMM_BODY
  uint4 o;
  o.x = ((unsigned)f2bf(a1) << 16) | f2bf(a0);
  o.y = ((unsigned)f2bf(a3) << 16) | f2bf(a2);
  o.z = ((unsigned)f2bf(a5) << 16) | f2bf(a4);
  o.w = ((unsigned)f2bf(a7) << 16) | f2bf(a6);
  y[t] = o;
}

// Layer-3 SpMM fused with the final average:
// out[rowmap(r)] = 0.25*(emb_fp32 + y1 + y2 + a); y3 never materialized.
__global__ __launch_bounds__(256) void spmm_final_kernel(
    const int*  __restrict__ row_ptr,
    const int2* __restrict__ edge_s,
    const uint4* __restrict__ x,          // = y2 (gather input)
    const uint4* __restrict__ y1u,
    const float4* __restrict__ user_emb,
    const float4* __restrict__ item_emb,
    float4* __restrict__ out) {
  int gt = blockIdx.x * 256 + threadIdx.x;
  if (gt < DV) out[(size_t)NUP1 * DV + gt] = make_float4(0.f, 0.f, 0.f, 0.f);
  if (gt >> 3 >= N_NODES) return;
  SPMM_BODY
  uint4 w1 = y1u[(size_t)r * DV8 + j];
  uint4 w2 = x  [(size_t)r * DV8 + j];    // y2 row (x aliases y2)
  int rm = (r < NUP1) ? r : r + 1;
  size_t eb = (size_t)r * DV + 2 * j;
  float4 f0, f1;
  if (r < NUP1) {
    f0 = user_emb[eb];
    f1 = user_emb[eb + 1];
  } else {
    size_t ib = (size_t)(r - 100000) * DV + 2 * j;
    f0 = item_emb[ib];
    f1 = item_emb[ib + 1];
  }
  float4 o0, o1;
  o0.x = 0.25f * (f0.x + bflo(w1.x) + bflo(w2.x) + a0);
  o0.y = 0.25f * (f0.y + bfhi(w1.x) + bfhi(w2.x) + a1);
  o0.z = 0.25f * (f0.z + bflo(w1.y) + bflo(w2.y) + a2);
  o0.w = 0.25f * (f0.w + bfhi(w1.y) + bfhi(w2.y) + a3);
  o1.x = 0.25f * (f1.x + bflo(w1.z) + bflo(w2.z) + a4);
  o1.y = 0.25f * (f1.y + bfhi(w1.z) + bfhi(w2.z) + a5);
  o1.z = 0.25f * (f1.z + bflo(w1.w) + bflo(w2.w) + a6);
  o1.w = 0.25f * (f1.w + bfhi(w1.w) + bfhi(w2.w) + a7);
  out[(size_t)rm * DV + 2 * j]     = o0;
  out[(size_t)rm * DV + 2 * j + 1] = o1;
}
#undef ACCUM

static inline char* align16(char* p) {
  return (char*)(((uintptr_t)p + 15) & ~(uintptr_t)15);
}

extern "C" void kernel_launch(void* const* d_in, const int* in_sizes, int n_in,
                              void* d_out, int out_size, void* d_ws, size_t ws_size,
                              hipStream_t stream) {
  const float* user_emb = (const float*)d_in[0];
  const float* item_emb = (const float*)d_in[1];
  const int*   rows     = (const int*)d_in[2];
  const int*   cols     = (const int*)d_in[3];
  const float* vals     = (const float*)d_in[4];
  const int    nnz      = in_sizes[2];

  const size_t xbytes = (size_t)N_NODES * D * sizeof(unsigned short); // 25.6 MB
  char* p = (char*)d_ws;
  ushort4* x0 = (ushort4*)p;  p += xbytes;
  ushort4* y1 = (ushort4*)p;  p += xbytes;
  ushort4* y2 = (ushort4*)p;  p += xbytes;
  ushort4* y3 = (ushort4*)p;  p += xbytes;  // scratch window for bucket_arr
  // bucket_arr aliases y2+y3 (51.2 MB window; needs 19.2 MB): fully consumed
  // by build_csr_chunk before layer-2 spmm writes y2.
  int2* bucket_arr = (int2*)y2;
  (void)y3;
  p = align16(p);
  int2* edge_s = (int2*)p;    p += (size_t)nnz * sizeof(int2);
  p = align16(p);
  int* row_ptr = (int*)p;     p += (size_t)(N_NODES + 1) * sizeof(int);
  p = align16(p);
  int* bucket_cnt = (int*)p;  p += (size_t)CNT_TOTAL * sizeof(int);

  float* out = (float*)d_out;

  const int row_elems = N_NODES * DV;                // 3,200,016
  const int node_grid = (row_elems + 255) / 256;     // 12501
  const int spmm_grid = (N_NODES * DV8 + 255) / 256; // 6251
  const int tile_grid = (nnz + T_TILE - 1) / T_TILE; // 489

  hipMemsetAsync(bucket_cnt, 0, (size_t)CNT_TOTAL * sizeof(int), stream);
  setup_kernel<<<tile_grid + node_grid, 256, 0, stream>>>(
      (const float4*)user_emb, (const float4*)item_emb, x0,
      rows, cols, vals, bucket_cnt, bucket_arr, nnz, tile_grid);
  build_csr_chunk<<<NCHUNK, 256, 0, stream>>>(
      bucket_cnt, bucket_arr, row_ptr, edge_s, nnz);

  spmm_bf16_kernel<<<spmm_grid, 256, 0, stream>>>(
      row_ptr, edge_s, (const uint4*)x0, (uint4*)y1);
  spmm_bf16_kernel<<<spmm_grid, 256, 0, stream>>>(
      row_ptr, edge_s, (const uint4*)y1, (uint4*)y2);
  spmm_final_kernel<<<spmm_grid, 256, 0, stream>>>(
      row_ptr, edge_s, (const uint4*)y2, (const uint4*)y1,
      (const float4*)user_emb, (const float4*)item_emb, (float4*)out);
}

// Round 7
// 301.358 us; speedup vs baseline: 1.1313x; 1.0138x over previous
//
#include <hip/hip_runtime.h>

// LightGCN, 3-layer propagation, 200001 nodes, D=64.
// Round 13: pre-pipeline tuning; all spmm hot loops untouched (r9
// verbatim, verified best: spmm_final stable 58.5us/3.87TB/s across 3
// structural variants = access-pattern plateau).
//  (a) build_csr at 512 threads, 1 thread/row: halves strided
//      histogram/scatter trip counts, doubles latency-hiding waves
//      (391 blocks ~1.5/CU -> per-block latency dominated).
//  (b) pass1 counter replicas REP 2->4: serialized per-line atomic
//      chain 245->122. SEGCAP=1536 = mean 1283 + 7 sigma.

#define N_NODES 200001
#define NUP1    100001            // NUM_USERS + 1
#define D       64
#define DV      16                // float4/ushort4 per row (init/final)
#define DV8     8                 // uint4 (8 bf16) per row (spmm)
#define CHUNK   512
#define NCHUNK  ((N_NODES + CHUNK - 1) / CHUNK)   // 391
#define T_TILE  4096              // edges per pass1 block
#define EPT     16                // edges per thread in pass1
#define CAP     6144              // bucket capacity
#define REP     4                 // counter replicas (by block & 3)
#define SEGCAP  (CAP / REP)       // 1536 (exp ~1283, +7 sigma)
#define CNT_STRIDE 16             // ints; one counter per 64B line
#define CNT_TOTAL  (NCHUNK * REP * CNT_STRIDE)   // 25024 ints

__device__ __forceinline__ unsigned short f2bf(float f) {
  unsigned u = __float_as_uint(f);
  unsigned r = (u + 0x7FFFu + ((u >> 16) & 1u)) >> 16;   // RNE
  return (unsigned short)r;
}
__device__ __forceinline__ float bf2f(unsigned short h) {
  return __uint_as_float(((unsigned)h) << 16);
}
__device__ __forceinline__ float bflo(unsigned u) { return __uint_as_float(u << 16); }
__device__ __forceinline__ float bfhi(unsigned u) { return __uint_as_float(u & 0xFFFF0000u); }

// Fused setup: blocks [0, tile_grid) run pass1 multisplit; blocks
// [tile_grid, ...) build x0 (bf16) from fp32 embeddings.
// bucket_cnt is pre-zeroed by hipMemsetAsync on the stream.
__global__ __launch_bounds__(256) void setup_kernel(
    const float4* __restrict__ user_emb,
    const float4* __restrict__ item_emb,
    ushort4* __restrict__ x0,
    const int*   __restrict__ rows,
    const int*   __restrict__ cols,
    const float* __restrict__ vals,
    int*  __restrict__ bucket_cnt,
    int2* __restrict__ bucket_arr,
    int nnz, int tile_grid) {
  __shared__ int lcount[NCHUNK];
  __shared__ int lbase[NCHUNK];
  int t = threadIdx.x;
  if (blockIdx.x >= tile_grid) {
    // ---- init path ----
    int idx = (blockIdx.x - tile_grid) * 256 + t;
    if (idx >= N_NODES * DV) return;
    int n = idx >> 4;
    int j = idx & 15;
    float4 v = (n < NUP1) ? user_emb[idx]
                          : item_emb[(size_t)(n - 100000) * DV + j];
    x0[idx] = make_ushort4(f2bf(v.x), f2bf(v.y), f2bf(v.z), f2bf(v.w));
    return;
  }
  // ---- pass1 multisplit path ----
  for (int i = t; i < NCHUNK; i += 256) lcount[i] = 0;
  __syncthreads();
  long base = (long)blockIdx.x * T_TILE;
  int rep = blockIdx.x & (REP - 1);
  int2 pk[EPT];
  int  meta[EPT];
#pragma unroll
  for (int k = 0; k < EPT; ++k) {
    long e = base + t + (long)k * 256;
    if (e < nnz) {
      int r = rows[e];
      int b = r >> 9;                          // chunk bucket (0..390)
      int rank = atomicAdd(&lcount[b], 1);     // LDS atomic
      pk[k] = make_int2(((r & 511) << 18) | cols[e], __float_as_int(vals[e]));
      meta[k] = (rank << 9) | b;               // rank<4096 (12b) | b (9b)
    } else {
      meta[k] = -1;
    }
  }
  __syncthreads();
  for (int b = t; b < NCHUNK; b += 256) {
    int c = lcount[b];
    lbase[b] = (c > 0)
        ? (b * CAP + rep * SEGCAP +
           atomicAdd(&bucket_cnt[(b * REP + rep) * CNT_STRIDE], c))
        : 0;
  }
  __syncthreads();
#pragma unroll
  for (int k = 0; k < EPT; ++k) {
    if (meta[k] >= 0) {
      int b = meta[k] & 511;
      int rank = meta[k] >> 9;
      bucket_arr[lbase[b] + rank] = pk[k];
    }
  }
}

// Fused per-chunk: inline 391-chunk prefix scan -> LDS histogram ->
// row scan (1 thread/row) -> row_ptr write -> scatter into final CSR
// order with LDS cursors. 512 threads; reads all 4 replica segments.
__global__ __launch_bounds__(512) void build_csr_chunk(
    const int*  __restrict__ bucket_cnt,
    const int2* __restrict__ bucket_arr,
    int*  __restrict__ row_ptr,
    int2* __restrict__ edge_s, int nnz) {
  __shared__ int lcnt[CHUNK];     // histogram, then cursors
  __shared__ int sh[512];
  __shared__ int cnarr[512];
  int b = blockIdx.x, t = threadIdx.x;
  // ---- Phase A: chunk-offset scan (each block computes full prefix) ----
  int cn = 0;
  if (t < NCHUNK) {
#pragma unroll
    for (int rsg = 0; rsg < REP; ++rsg)
      cn += bucket_cnt[(t * REP + rsg) * CNT_STRIDE];
  }
  cnarr[t] = cn;
  sh[t] = cn;
  __syncthreads();
  for (int o = 1; o < 512; o <<= 1) {
    int v = (t >= o) ? sh[t - o] : 0;
    __syncthreads();
    sh[t] += v;
    __syncthreads();
  }
  int chunk_off_b = sh[b] - cnarr[b];   // exclusive prefix at b
  if (b == 0 && t == 0) row_ptr[N_NODES] = nnz;
  __syncthreads();                      // sh reused below
  // ---- Phase B: histogram (4 segments) ----
  lcnt[t] = 0;
  __syncthreads();
  int ne[REP];
#pragma unroll
  for (int rsg = 0; rsg < REP; ++rsg)
    ne[rsg] = bucket_cnt[(b * REP + rsg) * CNT_STRIDE];
  const int2* ba = bucket_arr + (size_t)b * CAP;
#pragma unroll
  for (int rsg = 0; rsg < REP; ++rsg) {
    const int2* seg = ba + rsg * SEGCAP;
    for (int i = t; i < ne[rsg]; i += 512)
      atomicAdd(&lcnt[seg[i].x >> 18], 1);
  }
  __syncthreads();
  // ---- row scan: 1 thread per row ----
  int v = lcnt[t];
  sh[t] = v;
  __syncthreads();
  for (int o = 1; o < 512; o <<= 1) {
    int u = (t >= o) ? sh[t - o] : 0;
    __syncthreads();
    sh[t] += u;
    __syncthreads();
  }
  int run = sh[t] - v + chunk_off_b;    // exclusive prefix within chunk
  int row0 = b * CHUNK;
  if (row0 + t < N_NODES) row_ptr[row0 + t] = run;
  lcnt[t] = run;                        // becomes scatter cursor
  __syncthreads();
  // ---- scatter (4 segments) ----
#pragma unroll
  for (int rsg = 0; rsg < REP; ++rsg) {
    const int2* seg = ba + rsg * SEGCAP;
    for (int i = t; i < ne[rsg]; i += 512) {
      int2 ed = seg[i];
      int p = atomicAdd(&lcnt[ed.x >> 18], 1);
      edge_s[p] = make_int2(ed.x & 0x3FFFF, ed.y);
    }
  }
}

// Row-parallel bf16 SpMM: 8 lanes/row, 16 B (8 bf16 dims) per lane.
// Edge loop in clamped groups of 8: 8 record loads + 8 gathers issued
// back-to-back every iteration; padded slots contribute v=0.
// (round-9 code verbatim: best measured SpMM variant)
#define SPMM_BODY                                                   \
  int t = blockIdx.x * 256 + threadIdx.x;                           \
  int r = t >> 3;                                                   \
  int j = t & 7;                                                    \
  float a0 = 0.f, a1 = 0.f, a2 = 0.f, a3 = 0.f;                     \
  float a4 = 0.f, a5 = 0.f, a6 = 0.f, a7 = 0.f;                     \
  {                                                                 \
    int s = row_ptr[r];                                             \
    int e = row_ptr[r + 1];                                         \
    int last = e - 1;                                               \
    for (int g = s; g < e; g += 8) {                                \
      int2 e0 = edge_s[min(g + 0, last)];                           \
      int2 e1 = edge_s[min(g + 1, last)];                           \
      int2 e2 = edge_s[min(g + 2, last)];                           \
      int2 e3 = edge_s[min(g + 3, last)];                           \
      int2 e4 = edge_s[min(g + 4, last)];                           \
      int2 e5 = edge_s[min(g + 5, last)];                           \
      int2 e6 = edge_s[min(g + 6, last)];                           \
      int2 e7 = edge_s[min(g + 7, last)];                           \
      uint4 x0 = x[(size_t)e0.x * DV8 + j];                         \
      uint4 x1 = x[(size_t)e1.x * DV8 + j];                         \
      uint4 x2 = x[(size_t)e2.x * DV8 + j];                         \
      uint4 x3 = x[(size_t)e3.x * DV8 + j];                         \
      uint4 x4 = x[(size_t)e4.x * DV8 + j];                         \
      uint4 x5 = x[(size_t)e5.x * DV8 + j];                         \
      uint4 x6 = x[(size_t)e6.x * DV8 + j];                         \
      uint4 x7 = x[(size_t)e7.x * DV8 + j];                         \
      float v0 = __int_as_float(e0.y);                              \
      float v1 = (g + 1 < e) ? __int_as_float(e1.y) : 0.f;          \
      float v2 = (g + 2 < e) ? __int_as_float(e2.y) : 0.f;          \
      float v3 = (g + 3 < e) ? __int_as_float(e3.y) : 0.f;          \
      float v4 = (g + 4 < e) ? __int_as_float(e4.y) : 0.f;          \
      float v5 = (g + 5 < e) ? __int_as_float(e5.y) : 0.f;          \
      float v6 = (g + 6 < e) ? __int_as_float(e6.y) : 0.f;          \
      float v7 = (g + 7 < e) ? __int_as_float(e7.y) : 0.f;          \
      ACCUM(v0, x0); ACCUM(v1, x1); ACCUM(v2, x2); ACCUM(v3, x3);   \
      ACCUM(v4, x4); ACCUM(v5, x5); ACCUM(v6, x6); ACCUM(v7, x7);   \
    }                                                               \
  }

#define ACCUM(V, XV) {                                    \
    a0 += (V) * bflo((XV).x); a1 += (V) * bfhi((XV).x);   \
    a2 += (V) * bflo((XV).y); a3 += (V) * bfhi((XV).y);   \
    a4 += (V) * bflo((XV).z); a5 += (V) * bfhi((XV).z);   \
    a6 += (V) * bflo((XV).w); a7 += (V) * bfhi((XV).w); }

__global__ __launch_bounds__(256) void spmm_bf16_kernel(
    const int*  __restrict__ row_ptr,
    const int2* __restrict__ edge_s,
    const uint4* __restrict__ x,
    uint4*       __restrict__ y) {
  if ((blockIdx.x * 256 + threadIdx.x) >> 3 >= N_NODES) return;
  SPMM_BODY
  uint4 o;
  o.x = ((unsigned)f2bf(a1) << 16) | f2bf(a0);
  o.y = ((unsigned)f2bf(a3) << 16) | f2bf(a2);
  o.z = ((unsigned)f2bf(a5) << 16) | f2bf(a4);
  o.w = ((unsigned)f2bf(a7) << 16) | f2bf(a6);
  y[t] = o;
}

// Layer-3 SpMM fused with the final average:
// out[rowmap(r)] = 0.25*(emb_fp32 + y1 + y2 + a); y3 never materialized.
__global__ __launch_bounds__(256) void spmm_final_kernel(
    const int*  __restrict__ row_ptr,
    const int2* __restrict__ edge_s,
    const uint4* __restrict__ x,          // = y2 (gather input)
    const uint4* __restrict__ y1u,
    const float4* __restrict__ user_emb,
    const float4* __restrict__ item_emb,
    float4* __restrict__ out) {
  int gt = blockIdx.x * 256 + threadIdx.x;
  if (gt < DV) out[(size_t)NUP1 * DV + gt] = make_float4(0.f, 0.f, 0.f, 0.f);
  if (gt >> 3 >= N_NODES) return;
  SPMM_BODY
  uint4 w1 = y1u[(size_t)r * DV8 + j];
  uint4 w2 = x  [(size_t)r * DV8 + j];    // y2 row (x aliases y2)
  int rm = (r < NUP1) ? r : r + 1;
  size_t eb = (size_t)r * DV + 2 * j;
  float4 f0, f1;
  if (r < NUP1) {
    f0 = user_emb[eb];
    f1 = user_emb[eb + 1];
  } else {
    size_t ib = (size_t)(r - 100000) * DV + 2 * j;
    f0 = item_emb[ib];
    f1 = item_emb[ib + 1];
  }
  float4 o0, o1;
  o0.x = 0.25f * (f0.x + bflo(w1.x) + bflo(w2.x) + a0);
  o0.y = 0.25f * (f0.y + bfhi(w1.x) + bfhi(w2.x) + a1);
  o0.z = 0.25f * (f0.z + bflo(w1.y) + bflo(w2.y) + a2);
  o0.w = 0.25f * (f0.w + bfhi(w1.y) + bfhi(w2.y) + a3);
  o1.x = 0.25f * (f1.x + bflo(w1.z) + bflo(w2.z) + a4);
  o1.y = 0.25f * (f1.y + bfhi(w1.z) + bfhi(w2.z) + a5);
  o1.z = 0.25f * (f1.z + bflo(w1.w) + bflo(w2.w) + a6);
  o1.w = 0.25f * (f1.w + bfhi(w1.w) + bfhi(w2.w) + a7);
  out[(size_t)rm * DV + 2 * j]     = o0;
  out[(size_t)rm * DV + 2 * j + 1] = o1;
}
#undef ACCUM

static inline char* align16(char* p) {
  return (char*)(((uintptr_t)p + 15) & ~(uintptr_t)15);
}

extern "C" void kernel_launch(void* const* d_in, const int* in_sizes, int n_in,
                              void* d_out, int out_size, void* d_ws, size_t ws_size,
                              hipStream_t stream) {
  const float* user_emb = (const float*)d_in[0];
  const float* item_emb = (const float*)d_in[1];
  const int*   rows     = (const int*)d_in[2];
  const int*   cols     = (const int*)d_in[3];
  const float* vals     = (const float*)d_in[4];
  const int    nnz      = in_sizes[2];

  const size_t xbytes = (size_t)N_NODES * D * sizeof(unsigned short); // 25.6 MB
  char* p = (char*)d_ws;
  ushort4* x0 = (ushort4*)p;  p += xbytes;
  ushort4* y1 = (ushort4*)p;  p += xbytes;
  ushort4* y2 = (ushort4*)p;  p += xbytes;
  ushort4* y3 = (ushort4*)p;  p += xbytes;  // scratch window for bucket_arr
  // bucket_arr aliases y2+y3 (51.2 MB window; needs 19.2 MB): fully consumed
  // by build_csr_chunk before layer-2 spmm writes y2.
  int2* bucket_arr = (int2*)y2;
  (void)y3;
  p = align16(p);
  int2* edge_s = (int2*)p;    p += (size_t)nnz * sizeof(int2);
  p = align16(p);
  int* row_ptr = (int*)p;     p += (size_t)(N_NODES + 1) * sizeof(int);
  p = align16(p);
  int* bucket_cnt = (int*)p;  p += (size_t)CNT_TOTAL * sizeof(int);

  float* out = (float*)d_out;

  const int row_elems = N_NODES * DV;                // 3,200,016
  const int node_grid = (row_elems + 255) / 256;     // 12501
  const int spmm_grid = (N_NODES * DV8 + 255) / 256; // 6251
  const int tile_grid = (nnz + T_TILE - 1) / T_TILE; // 489

  hipMemsetAsync(bucket_cnt, 0, (size_t)CNT_TOTAL * sizeof(int), stream);
  setup_kernel<<<tile_grid + node_grid, 256, 0, stream>>>(
      (const float4*)user_emb, (const float4*)item_emb, x0,
      rows, cols, vals, bucket_cnt, bucket_arr, nnz, tile_grid);
  build_csr_chunk<<<NCHUNK, 512, 0, stream>>>(
      bucket_cnt, bucket_arr, row_ptr, edge_s, nnz);

  spmm_bf16_kernel<<<spmm_grid, 256, 0, stream>>>(
      row_ptr, edge_s, (const uint4*)x0, (uint4*)y1);
  spmm_bf16_kernel<<<spmm_grid, 256, 0, stream>>>(
      row_ptr, edge_s, (const uint4*)y1, (uint4*)y2);
  spmm_final_kernel<<<spmm_grid, 256, 0, stream>>>(
      row_ptr, edge_s, (const uint4*)y2, (const uint4*)y1,
      (const float4*)user_emb, (const float4*)item_emb, (float4*)out);
}

// Round 8
// 300.074 us; speedup vs baseline: 1.1361x; 1.0043x over previous
//
#include <hip/hip_runtime.h>

// LightGCN, 3-layer propagation, 200001 nodes, D=64.
// Round 14: pre-pipeline latency tuning; spmm hot loops untouched
// (r9 verbatim; spmm_final pinned 58.3-59.3us/3.87TB/s across 4
// structural variants = access-pattern plateau).
//  (a) build_csr: int4-paired record loads in hist+scatter (2 recs/
//      thread/iter, 16B-aligned) -> halves dependent iteration count
//      of the latency-bound loops.
//  (b) pass1 REP 4->8: per-line atomic chain 122->61. SEGCAP 832 =
//      mean 640 + 7.6 sigma; CAP 6656 -> bucket_arr 20.8MB (fits
//      the y2/y3 51.2MB alias window).

#define N_NODES 200001
#define NUP1    100001            // NUM_USERS + 1
#define D       64
#define DV      16                // float4/ushort4 per row (init/final)
#define DV8     8                 // uint4 (8 bf16) per row (spmm)
#define CHUNK   512
#define NCHUNK  ((N_NODES + CHUNK - 1) / CHUNK)   // 391
#define T_TILE  4096              // edges per pass1 block
#define EPT     16                // edges per thread in pass1
#define CAP     6656              // bucket capacity (8 * SEGCAP)
#define REP     8                 // counter replicas (by block & 7)
#define SEGCAP  (CAP / REP)       // 832 (exp ~640, +7.6 sigma)
#define CNT_STRIDE 16             // ints; one counter per 64B line
#define CNT_TOTAL  (NCHUNK * REP * CNT_STRIDE)   // 50048 ints

__device__ __forceinline__ unsigned short f2bf(float f) {
  unsigned u = __float_as_uint(f);
  unsigned r = (u + 0x7FFFu + ((u >> 16) & 1u)) >> 16;   // RNE
  return (unsigned short)r;
}
__device__ __forceinline__ float bf2f(unsigned short h) {
  return __uint_as_float(((unsigned)h) << 16);
}
__device__ __forceinline__ float bflo(unsigned u) { return __uint_as_float(u << 16); }
__device__ __forceinline__ float bfhi(unsigned u) { return __uint_as_float(u & 0xFFFF0000u); }

// Fused setup: blocks [0, tile_grid) run pass1 multisplit; blocks
// [tile_grid, ...) build x0 (bf16) from fp32 embeddings.
// bucket_cnt is pre-zeroed by hipMemsetAsync on the stream.
__global__ __launch_bounds__(256) void setup_kernel(
    const float4* __restrict__ user_emb,
    const float4* __restrict__ item_emb,
    ushort4* __restrict__ x0,
    const int*   __restrict__ rows,
    const int*   __restrict__ cols,
    const float* __restrict__ vals,
    int*  __restrict__ bucket_cnt,
    int2* __restrict__ bucket_arr,
    int nnz, int tile_grid) {
  __shared__ int lcount[NCHUNK];
  __shared__ int lbase[NCHUNK];
  int t = threadIdx.x;
  if (blockIdx.x >= tile_grid) {
    // ---- init path ----
    int idx = (blockIdx.x - tile_grid) * 256 + t;
    if (idx >= N_NODES * DV) return;
    int n = idx >> 4;
    int j = idx & 15;
    float4 v = (n < NUP1) ? user_emb[idx]
                          : item_emb[(size_t)(n - 100000) * DV + j];
    x0[idx] = make_ushort4(f2bf(v.x), f2bf(v.y), f2bf(v.z), f2bf(v.w));
    return;
  }
  // ---- pass1 multisplit path ----
  for (int i = t; i < NCHUNK; i += 256) lcount[i] = 0;
  __syncthreads();
  long base = (long)blockIdx.x * T_TILE;
  int rep = blockIdx.x & (REP - 1);
  int2 pk[EPT];
  int  meta[EPT];
#pragma unroll
  for (int k = 0; k < EPT; ++k) {
    long e = base + t + (long)k * 256;
    if (e < nnz) {
      int r = rows[e];
      int b = r >> 9;                          // chunk bucket (0..390)
      int rank = atomicAdd(&lcount[b], 1);     // LDS atomic
      pk[k] = make_int2(((r & 511) << 18) | cols[e], __float_as_int(vals[e]));
      meta[k] = (rank << 9) | b;               // rank (12b) | b (9b)
    } else {
      meta[k] = -1;
    }
  }
  __syncthreads();
  for (int b = t; b < NCHUNK; b += 256) {
    int c = lcount[b];
    lbase[b] = (c > 0)
        ? (b * CAP + rep * SEGCAP +
           atomicAdd(&bucket_cnt[(b * REP + rep) * CNT_STRIDE], c))
        : 0;
  }
  __syncthreads();
#pragma unroll
  for (int k = 0; k < EPT; ++k) {
    if (meta[k] >= 0) {
      int b = meta[k] & 511;
      int rank = meta[k] >> 9;
      bucket_arr[lbase[b] + rank] = pk[k];
    }
  }
}

// Fused per-chunk: inline 391-chunk prefix scan -> LDS histogram ->
// row scan (1 thread/row) -> row_ptr write -> scatter into final CSR
// order with LDS cursors. 512 threads; 8 replica segments; hist and
// scatter consume records in int4 pairs (2 records/thread/iter).
__global__ __launch_bounds__(512) void build_csr_chunk(
    const int*  __restrict__ bucket_cnt,
    const int2* __restrict__ bucket_arr,
    int*  __restrict__ row_ptr,
    int2* __restrict__ edge_s, int nnz) {
  __shared__ int lcnt[CHUNK];     // histogram, then cursors
  __shared__ int sh[512];
  __shared__ int cnarr[512];
  int b = blockIdx.x, t = threadIdx.x;
  // ---- Phase A: chunk-offset scan (each block computes full prefix) ----
  int cn = 0;
  if (t < NCHUNK) {
#pragma unroll
    for (int rsg = 0; rsg < REP; ++rsg)
      cn += bucket_cnt[(t * REP + rsg) * CNT_STRIDE];
  }
  cnarr[t] = cn;
  sh[t] = cn;
  __syncthreads();
  for (int o = 1; o < 512; o <<= 1) {
    int v = (t >= o) ? sh[t - o] : 0;
    __syncthreads();
    sh[t] += v;
    __syncthreads();
  }
  int chunk_off_b = sh[b] - cnarr[b];   // exclusive prefix at b
  if (b == 0 && t == 0) row_ptr[N_NODES] = nnz;
  __syncthreads();                      // sh reused below
  // ---- Phase B: histogram (8 segments, int4-paired) ----
  lcnt[t] = 0;
  __syncthreads();
  int ne[REP];
#pragma unroll
  for (int rsg = 0; rsg < REP; ++rsg)
    ne[rsg] = bucket_cnt[(b * REP + rsg) * CNT_STRIDE];
  const int2* ba = bucket_arr + (size_t)b * CAP;
#pragma unroll
  for (int rsg = 0; rsg < REP; ++rsg) {
    const int2* seg = ba + rsg * SEGCAP;
    int n = ne[rsg];
    for (int i = 2 * t; i < n; i += 1024) {
      if (i + 1 < n) {
        int4 two = *(const int4*)(seg + i);   // 16B-aligned: SEGCAP/CAP even
        atomicAdd(&lcnt[two.x >> 18], 1);
        atomicAdd(&lcnt[two.z >> 18], 1);
      } else {
        atomicAdd(&lcnt[seg[i].x >> 18], 1);
      }
    }
  }
  __syncthreads();
  // ---- row scan: 1 thread per row ----
  int v = lcnt[t];
  sh[t] = v;
  __syncthreads();
  for (int o = 1; o < 512; o <<= 1) {
    int u = (t >= o) ? sh[t - o] : 0;
    __syncthreads();
    sh[t] += u;
    __syncthreads();
  }
  int run = sh[t] - v + chunk_off_b;    // exclusive prefix within chunk
  int row0 = b * CHUNK;
  if (row0 + t < N_NODES) row_ptr[row0 + t] = run;
  lcnt[t] = run;                        // becomes scatter cursor
  __syncthreads();
  // ---- scatter (8 segments, int4-paired) ----
#pragma unroll
  for (int rsg = 0; rsg < REP; ++rsg) {
    const int2* seg = ba + rsg * SEGCAP;
    int n = ne[rsg];
    for (int i = 2 * t; i < n; i += 1024) {
      if (i + 1 < n) {
        int4 two = *(const int4*)(seg + i);
        int p0 = atomicAdd(&lcnt[two.x >> 18], 1);
        edge_s[p0] = make_int2(two.x & 0x3FFFF, two.y);
        int p1 = atomicAdd(&lcnt[two.z >> 18], 1);
        edge_s[p1] = make_int2(two.z & 0x3FFFF, two.w);
      } else {
        int2 ed = seg[i];
        int p = atomicAdd(&lcnt[ed.x >> 18], 1);
        edge_s[p] = make_int2(ed.x & 0x3FFFF, ed.y);
      }
    }
  }
}

// Row-parallel bf16 SpMM: 8 lanes/row, 16 B (8 bf16 dims) per lane.
// Edge loop in clamped groups of 8: 8 record loads + 8 gathers issued
// back-to-back every iteration; padded slots contribute v=0.
// (round-9 code verbatim: best measured SpMM variant)
#define SPMM_BODY                                                   \
  int t = blockIdx.x * 256 + threadIdx.x;                           \
  int r = t >> 3;                                                   \
  int j = t & 7;                                                    \
  float a0 = 0.f, a1 = 0.f, a2 = 0.f, a3 = 0.f;                     \
  float a4 = 0.f, a5 = 0.f, a6 = 0.f, a7 = 0.f;                     \
  {                                                                 \
    int s = row_ptr[r];                                             \
    int e = row_ptr[r + 1];                                         \
    int last = e - 1;                                               \
    for (int g = s; g < e; g += 8) {                                \
      int2 e0 = edge_s[min(g + 0, last)];                           \
      int2 e1 = edge_s[min(g + 1, last)];                           \
      int2 e2 = edge_s[min(g + 2, last)];                           \
      int2 e3 = edge_s[min(g + 3, last)];                           \
      int2 e4 = edge_s[min(g + 4, last)];                           \
      int2 e5 = edge_s[min(g + 5, last)];                           \
      int2 e6 = edge_s[min(g + 6, last)];                           \
      int2 e7 = edge_s[min(g + 7, last)];                           \
      uint4 x0 = x[(size_t)e0.x * DV8 + j];                         \
      uint4 x1 = x[(size_t)e1.x * DV8 + j];                         \
      uint4 x2 = x[(size_t)e2.x * DV8 + j];                         \
      uint4 x3 = x[(size_t)e3.x * DV8 + j];                         \
      uint4 x4 = x[(size_t)e4.x * DV8 + j];                         \
      uint4 x5 = x[(size_t)e5.x * DV8 + j];                         \
      uint4 x6 = x[(size_t)e6.x * DV8 + j];                         \
      uint4 x7 = x[(size_t)e7.x * DV8 + j];                         \
      float v0 = __int_as_float(e0.y);                              \
      float v1 = (g + 1 < e) ? __int_as_float(e1.y) : 0.f;          \
      float v2 = (g + 2 < e) ? __int_as_float(e2.y) : 0.f;          \
      float v3 = (g + 3 < e) ? __int_as_float(e3.y) : 0.f;          \
      float v4 = (g + 4 < e) ? __int_as_float(e4.y) : 0.f;          \
      float v5 = (g + 5 < e) ? __int_as_float(e5.y) : 0.f;          \
      float v6 = (g + 6 < e) ? __int_as_float(e6.y) : 0.f;          \
      float v7 = (g + 7 < e) ? __int_as_float(e7.y) : 0.f;          \
      ACCUM(v0, x0); ACCUM(v1, x1); ACCUM(v2, x2); ACCUM(v3, x3);   \
      ACCUM(v4, x4); ACCUM(v5, x5); ACCUM(v6, x6); ACCUM(v7, x7);   \
    }                                                               \
  }

#define ACCUM(V, XV) {                                    \
    a0 += (V) * bflo((XV).x); a1 += (V) * bfhi((XV).x);   \
    a2 += (V) * bflo((XV).y); a3 += (V) * bfhi((XV).y);   \
    a4 += (V) * bflo((XV).z); a5 += (V) * bfhi((XV).z);   \
    a6 += (V) * bflo((XV).w); a7 += (V) * bfhi((XV).w); }

__global__ __launch_bounds__(256) void spmm_bf16_kernel(
    const int*  __restrict__ row_ptr,
    const int2* __restrict__ edge_s,
    const uint4* __restrict__ x,
    uint4*       __restrict__ y) {
  if ((blockIdx.x * 256 + threadIdx.x) >> 3 >= N_NODES) return;
  SPMM_BODY
  uint4 o;
  o.x = ((unsigned)f2bf(a1) << 16) | f2bf(a0);
  o.y = ((unsigned)f2bf(a3) << 16) | f2bf(a2);
  o.z = ((unsigned)f2bf(a5) << 16) | f2bf(a4);
  o.w = ((unsigned)f2bf(a7) << 16) | f2bf(a6);
  y[t] = o;
}

// Layer-3 SpMM fused with the final average:
// out[rowmap(r)] = 0.25*(emb_fp32 + y1 + y2 + a); y3 never materialized.
__global__ __launch_bounds__(256) void spmm_final_kernel(
    const int*  __restrict__ row_ptr,
    const int2* __restrict__ edge_s,
    const uint4* __restrict__ x,          // = y2 (gather input)
    const uint4* __restrict__ y1u,
    const float4* __restrict__ user_emb,
    const float4* __restrict__ item_emb,
    float4* __restrict__ out) {
  int gt = blockIdx.x * 256 + threadIdx.x;
  if (gt < DV) out[(size_t)NUP1 * DV + gt] = make_float4(0.f, 0.f, 0.f, 0.f);
  if (gt >> 3 >= N_NODES) return;
  SPMM_BODY
  uint4 w1 = y1u[(size_t)r * DV8 + j];
  uint4 w2 = x  [(size_t)r * DV8 + j];    // y2 row (x aliases y2)
  int rm = (r < NUP1) ? r : r + 1;
  size_t eb = (size_t)r * DV + 2 * j;
  float4 f0, f1;
  if (r < NUP1) {
    f0 = user_emb[eb];
    f1 = user_emb[eb + 1];
  } else {
    size_t ib = (size_t)(r - 100000) * DV + 2 * j;
    f0 = item_emb[ib];
    f1 = item_emb[ib + 1];
  }
  float4 o0, o1;
  o0.x = 0.25f * (f0.x + bflo(w1.x) + bflo(w2.x) + a0);
  o0.y = 0.25f * (f0.y + bfhi(w1.x) + bfhi(w2.x) + a1);
  o0.z = 0.25f * (f0.z + bflo(w1.y) + bflo(w2.y) + a2);
  o0.w = 0.25f * (f0.w + bfhi(w1.y) + bfhi(w2.y) + a3);
  o1.x = 0.25f * (f1.x + bflo(w1.z) + bflo(w2.z) + a4);
  o1.y = 0.25f * (f1.y + bfhi(w1.z) + bfhi(w2.z) + a5);
  o1.z = 0.25f * (f1.z + bflo(w1.w) + bflo(w2.w) + a6);
  o1.w = 0.25f * (f1.w + bfhi(w1.w) + bfhi(w2.w) + a7);
  out[(size_t)rm * DV + 2 * j]     = o0;
  out[(size_t)rm * DV + 2 * j + 1] = o1;
}
#undef ACCUM

static inline char* align16(char* p) {
  return (char*)(((uintptr_t)p + 15) & ~(uintptr_t)15);
}

extern "C" void kernel_launch(void* const* d_in, const int* in_sizes, int n_in,
                              void* d_out, int out_size, void* d_ws, size_t ws_size,
                              hipStream_t stream) {
  const float* user_emb = (const float*)d_in[0];
  const float* item_emb = (const float*)d_in[1];
  const int*   rows     = (const int*)d_in[2];
  const int*   cols     = (const int*)d_in[3];
  const float* vals     = (const float*)d_in[4];
  const int    nnz      = in_sizes[2];

  const size_t xbytes = (size_t)N_NODES * D * sizeof(unsigned short); // 25.6 MB
  char* p = (char*)d_ws;
  ushort4* x0 = (ushort4*)p;  p += xbytes;
  ushort4* y1 = (ushort4*)p;  p += xbytes;
  ushort4* y2 = (ushort4*)p;  p += xbytes;
  ushort4* y3 = (ushort4*)p;  p += xbytes;  // scratch window for bucket_arr
  // bucket_arr aliases y2+y3 (51.2 MB window; needs 20.8 MB): fully consumed
  // by build_csr_chunk before layer-2 spmm writes y2.
  int2* bucket_arr = (int2*)y2;
  (void)y3;
  p = align16(p);
  int2* edge_s = (int2*)p;    p += (size_t)nnz * sizeof(int2);
  p = align16(p);
  int* row_ptr = (int*)p;     p += (size_t)(N_NODES + 1) * sizeof(int);
  p = align16(p);
  int* bucket_cnt = (int*)p;  p += (size_t)CNT_TOTAL * sizeof(int);

  float* out = (float*)d_out;

  const int row_elems = N_NODES * DV;                // 3,200,016
  const int node_grid = (row_elems + 255) / 256;     // 12501
  const int spmm_grid = (N_NODES * DV8 + 255) / 256; // 6251
  const int tile_grid = (nnz + T_TILE - 1) / T_TILE; // 489

  hipMemsetAsync(bucket_cnt, 0, (size_t)CNT_TOTAL * sizeof(int), stream);
  setup_kernel<<<tile_grid + node_grid, 256, 0, stream>>>(
      (const float4*)user_emb, (const float4*)item_emb, x0,
      rows, cols, vals, bucket_cnt, bucket_arr, nnz, tile_grid);
  build_csr_chunk<<<NCHUNK, 512, 0, stream>>>(
      bucket_cnt, bucket_arr, row_ptr, edge_s, nnz);

  spmm_bf16_kernel<<<spmm_grid, 256, 0, stream>>>(
      row_ptr, edge_s, (const uint4*)x0, (uint4*)y1);
  spmm_bf16_kernel<<<spmm_grid, 256, 0, stream>>>(
      row_ptr, edge_s, (const uint4*)y1, (uint4*)y2);
  spmm_final_kernel<<<spmm_grid, 256, 0, stream>>>(
      row_ptr, edge_s, (const uint4*)y2, (const uint4*)y1,
      (const float4*)user_emb, (const float4*)item_emb, (float4*)out);
}